// Round 11
// baseline (323.070 us; speedup 1.0000x reference)
//
#include <hip/hip_runtime.h>

// B=16, N=512, T=64, D=64, H=8, K=3, DK=8
// grid = 8192 blocks (one per (b,n)), 256 threads (4 waves), 3 blocks/CU
// R11 = R10 + out stores routed through LDS (dead kb/vT region) as f32,
// read back wave-coalesced, emitted as nontemporal f32x4 (1024B/inst).

#define OUT_ELEMS 33554432ull   // B*N*T*D

typedef unsigned short u16;
typedef unsigned int u32;
typedef __attribute__((ext_vector_type(8))) short short8;
typedef __attribute__((ext_vector_type(4))) float f32x4;

__device__ __forceinline__ u16 f2b(float f) {  // f32 -> bf16 RNE
  u32 u = __float_as_uint(f);
  return (u16)((u + 0x7fffu + ((u >> 16) & 1u)) >> 16);
}
__device__ __forceinline__ float b2f_lo(u32 u) { return __uint_as_float(u << 16); }
__device__ __forceinline__ float b2f_hi(u32 u) { return __uint_as_float(u & 0xffff0000u); }

// ws (ushort) layout, MFMA fragment order (lane l = (idx>>3)&63, elem e = idx&7):
//  wsq [0,12288):     frag f=(j*2+kk)*4+nt : Wq[d=nt*16+(l&15)][c=kk*32+(l>>4)*8+e][j]
//  wsk [12288,24576): same for Wk
//  wsv [24576,28672): frag f=w*2+kk (A-op): Wv[d=16w+(l&15)][c=kk*32+(l>>4)*8+e]
//  wso [28672,32768): frag f=kk*4+nt (B-op): Wo[dp=nt*16+(l&15)][c=kk*32+(l>>4)*8+e]
__global__ __launch_bounds__(256) void prep_weights(
    const float* __restrict__ Wq, const float* __restrict__ Wk,
    const float* __restrict__ Wv, const float* __restrict__ Wo,
    u16* __restrict__ ws) {
  int i = blockIdx.x * 256 + threadIdx.x;  // 0..32767
  int lane = (i >> 3) & 63;
  int e = i & 7;
  int m15 = lane & 15, g = lane >> 4;
  if (i < 12288) {
    int f = i >> 9;  // 0..23
    int j = f >> 3, kk = (f >> 2) & 1, nt = f & 3;
    int d = nt * 16 + m15, c = kk * 32 + g * 8 + e;
    ws[i] = f2b(Wq[(d * 64 + c) * 3 + j]);
  } else if (i < 24576) {
    int f = (i - 12288) >> 9;
    int j = f >> 3, kk = (f >> 2) & 1, nt = f & 3;
    int d = nt * 16 + m15, c = kk * 32 + g * 8 + e;
    ws[i] = f2b(Wk[(d * 64 + c) * 3 + j]);
  } else if (i < 28672) {
    int f = (i - 24576) >> 9;  // 0..7
    int w = f >> 1, kk = f & 1;
    int d = 16 * w + m15, c = kk * 32 + g * 8 + e;
    ws[i] = f2b(Wv[d * 64 + c]);
  } else if (i < 32768) {
    int f = (i - 28672) >> 9;  // 0..7
    int kk = f >> 2, nt = f & 3;
    int dp = nt * 16 + m15, c = kk * 32 + g * 8 + e;
    ws[i] = f2b(Wo[dp * 64 + c]);
  }
}

__global__ __launch_bounds__(256, 3) void fused_attn(
    const float* __restrict__ q_in, const float* __restrict__ k_in,
    const float* __restrict__ v_in, const int* __restrict__ mask,
    const u16* __restrict__ ws,
    const float* __restrict__ bq, const float* __restrict__ bk,
    const float* __restrict__ bv, const float* __restrict__ bo,
    float* __restrict__ out, float* __restrict__ p_out) {
  // One explicitly-laid-out LDS pool (u16 units), row pitch 72 bf16 (144B):
  //  xb [0, 4752)      : staging rows 66 (rows 0,1 zero-pad); later pb
  //  qb [4752, 9360)   : q (scaled) [t][d]
  //  kb [9360, 13968)  : k [s][d]        -- dead after head loop
  //  vT [13968, 18576) : v^T [d][s]      -- dead after head loop
  //  xo [18576, 23184) : attn out x [t][d]
  //  fstage = (float*)(LDS + 9360): out f32 [64][pitch 68]  (17408 B <= kb+vT 18432 B)
  __shared__ __align__(16) u16 LDS[23184];
  u16* xb = LDS;
  u16* qb = LDS + 4752;
  u16* kb = LDS + 9360;
  u16* vT = LDS + 13968;
  u16* xo = LDS + 18576;

  const int tid = threadIdx.x;
  const int bid = blockIdx.x;   // b*512 + n
  const int b = bid >> 9;
  const int l = tid & 63;
  const int w = tid >> 6;       // wave 0..3
  const int g = l >> 4;         // lane group 0..3
  const int m15 = l & 15;

  const u16* wsq = ws;
  const u16* wsk = ws + 12288;
  const u16* wsv = ws + 24576;
  const u16* wso = ws + 28672;

  const short8 z8 = {0, 0, 0, 0, 0, 0, 0, 0};

  // zero xb pad rows 0,1: 2 rows * 72 u16 = 144 u16 = 72 dwords
  if (tid < 72) ((u32*)xb)[tid] = 0u;

  // ---------- helpers as lambdas ----------
  auto stage = [&](const float* __restrict__ src) {
#pragma unroll
    for (int cc = 0; cc < 2; cc++) {
      int c = tid * 2 + cc;              // 0..511 chunks of 8 floats
      const float* p = src + c * 8;
      float4 x0 = *(const float4*)(p);
      float4 x1 = *(const float4*)(p + 4);
      u32 p0 = (u32)f2b(x0.x) | ((u32)f2b(x0.y) << 16);
      u32 p1 = (u32)f2b(x0.z) | ((u32)f2b(x0.w) << 16);
      u32 p2 = (u32)f2b(x1.x) | ((u32)f2b(x1.y) << 16);
      u32 p3 = (u32)f2b(x1.z) | ((u32)f2b(x1.w) << 16);
      int r = c >> 3, k8 = (c & 7) * 8;
      *(uint4*)(xb + (r + 2) * 72 + k8) = make_uint4(p0, p1, p2, p3);
    }
  };

  auto conv = [&](const u16* __restrict__ wpack, const float* __restrict__ bias,
                  float scale, u16* __restrict__ dst) {
    f32x4 acc[4];
#pragma unroll
    for (int nt = 0; nt < 4; nt++) {
      float bb = bias[nt * 16 + m15];
      acc[nt] = (f32x4){bb, bb, bb, bb};
    }
#pragma unroll
    for (int j = 0; j < 3; j++) {
#pragma unroll
      for (int kk = 0; kk < 2; kk++) {
        short8 a = *(const short8*)(xb + (16 * w + m15 + j) * 72 + kk * 32 + g * 8);
#pragma unroll
        for (int nt = 0; nt < 4; nt++) {
          short8 bf = *(const short8*)(wpack + (size_t)((j * 2 + kk) * 4 + nt) * 512 + l * 8);
          acc[nt] = __builtin_amdgcn_mfma_f32_16x16x32_bf16(a, bf, acc[nt], 0, 0, 0);
        }
      }
    }
#pragma unroll
    for (int nt = 0; nt < 4; nt++)
#pragma unroll
      for (int r = 0; r < 4; r++)
        dst[(16 * w + g * 4 + r) * 72 + nt * 16 + m15] = f2b(acc[nt][r] * scale);
  };

  // ---------- stage q, conv q -> qb (scale folded) ----------
  stage(q_in + (size_t)bid * 4096);
  __syncthreads();
  conv(wsq, bq, 0.35355339059327373f, qb);
  __syncthreads();

  // ---------- stage k, conv k -> kb ----------
  stage(k_in + (size_t)bid * 4096);
  __syncthreads();
  conv(wsk, bk, 1.0f, kb);
  __syncthreads();

  // ---------- stage v, v-proj -> vT[d][s] ----------
  stage(v_in + (size_t)bid * 4096);
  __syncthreads();
  {
    f32x4 acc[4];
    float bm0 = bv[16 * w + g * 4 + 0], bm1 = bv[16 * w + g * 4 + 1];
    float bm2 = bv[16 * w + g * 4 + 2], bm3 = bv[16 * w + g * 4 + 3];
#pragma unroll
    for (int nt = 0; nt < 4; nt++) acc[nt] = (f32x4){bm0, bm1, bm2, bm3};
#pragma unroll
    for (int kk = 0; kk < 2; kk++) {
      short8 a = *(const short8*)(wsv + (size_t)(w * 2 + kk) * 512 + l * 8);
#pragma unroll
      for (int nt = 0; nt < 4; nt++) {
        short8 bf = *(const short8*)(xb + (nt * 16 + m15 + 2) * 72 + kk * 32 + g * 8);
        acc[nt] = __builtin_amdgcn_mfma_f32_16x16x32_bf16(a, bf, acc[nt], 0, 0, 0);
      }
    }
#pragma unroll
    for (int nt = 0; nt < 4; nt++)
#pragma unroll
      for (int r = 0; r < 4; r++)
        vT[(16 * w + g * 4 + r) * 72 + nt * 16 + m15] = f2b(acc[nt][r]);
  }

  // mask bits: bit nt*4+r = mask[b][t=16w+g*4+r][s=nt*16+m15]
  u32 mb = 0;
#pragma unroll
  for (int nt = 0; nt < 4; nt++)
#pragma unroll
    for (int r = 0; r < 4; r++)
      if (mask[(size_t)b * 4096 + (16 * w + g * 4 + r) * 64 + nt * 16 + m15])
        mb |= 1u << (nt * 4 + r);
  __syncthreads();  // vT complete (cross-wave); xb free -> pb

  u16* pb = xb;  // P staging [t][s] bf16, rows 0..63; intra-wave use only

  // ---------- head loop: ZERO barriers (qb/pb/xo rows are wave-private; vT,kb read-only) ----------
#pragma unroll 1
  for (int h = 0; h < 8; h++) {
    // QK^T: K=8 padded to 32 (only lane-group 0 carries data)
    short8 aq = *(const short8*)(qb + (16 * w + m15) * 72 + h * 8);
    if (g != 0) aq = z8;
    f32x4 s4[4];
#pragma unroll
    for (int nt = 0; nt < 4; nt++) {
      short8 bk8 = *(const short8*)(kb + (nt * 16 + m15) * 72 + h * 8);
      if (g != 0) bk8 = z8;
      f32x4 zero = {0.f, 0.f, 0.f, 0.f};
      s4[nt] = __builtin_amdgcn_mfma_f32_16x16x32_bf16(aq, bk8, zero, 0, 0, 0);
    }
    // masked softmax over s (row = t fixed per (g,r); cols across 16 lanes x 4 nt)
    float e[4][4];
    float rs0 = 0.f, rs1 = 0.f, rs2 = 0.f, rs3 = 0.f;
#pragma unroll
    for (int nt = 0; nt < 4; nt++) {
      e[nt][0] = (mb & (1u << (nt * 4 + 0))) ? __expf(s4[nt][0]) : 0.f;
      e[nt][1] = (mb & (1u << (nt * 4 + 1))) ? __expf(s4[nt][1]) : 0.f;
      e[nt][2] = (mb & (1u << (nt * 4 + 2))) ? __expf(s4[nt][2]) : 0.f;
      e[nt][3] = (mb & (1u << (nt * 4 + 3))) ? __expf(s4[nt][3]) : 0.f;
      rs0 += e[nt][0]; rs1 += e[nt][1]; rs2 += e[nt][2]; rs3 += e[nt][3];
    }
#pragma unroll
    for (int off = 1; off <= 8; off <<= 1) {
      rs0 += __shfl_xor(rs0, off);
      rs1 += __shfl_xor(rs1, off);
      rs2 += __shfl_xor(rs2, off);
      rs3 += __shfl_xor(rs3, off);
    }
    float ri0 = __fdividef(1.f, rs0 + 1e-30f);
    float ri1 = __fdividef(1.f, rs1 + 1e-30f);
    float ri2 = __fdividef(1.f, rs2 + 1e-30f);
    float ri3 = __fdividef(1.f, rs3 + 1e-30f);
    // write P (bf16) to LDS; p_out produced from pb below, coalesced + nontemporal
#pragma unroll
    for (int nt = 0; nt < 4; nt++) {
      pb[(16 * w + g * 4 + 0) * 72 + nt * 16 + m15] = f2b(e[nt][0] * ri0);
      pb[(16 * w + g * 4 + 1) * 72 + nt * 16 + m15] = f2b(e[nt][1] * ri1);
      pb[(16 * w + g * 4 + 2) * 72 + nt * 16 + m15] = f2b(e[nt][2] * ri2);
      pb[(16 * w + g * 4 + 3) * 72 + nt * 16 + m15] = f2b(e[nt][3] * ri3);
    }
    // coalesced p_out: lane l -> row 16w + ro*4 + g, cols m15*4..+3
    // per instruction: 64 lanes cover 1024B contiguous (8 full 128B lines)
    float* pg = p_out + (((size_t)bid * 8 + h) * 4096);
#pragma unroll
    for (int ro = 0; ro < 4; ro++) {
      int row = 16 * w + ro * 4 + g;
      uint2 pv2 = *(const uint2*)(pb + row * 72 + m15 * 4);
      f32x4 f = {b2f_lo(pv2.x), b2f_hi(pv2.x), b2f_lo(pv2.y), b2f_hi(pv2.y)};
      __builtin_nontemporal_store(f, (f32x4*)(pg + row * 64 + m15 * 4));
    }
    // PV: x[t][h*8+dk] = sum_s P[t][s] v[s][h*8+dk]; N-cols 8..15 duplicated, discarded
    f32x4 xacc = {0.f, 0.f, 0.f, 0.f};
#pragma unroll
    for (int kk = 0; kk < 2; kk++) {
      short8 ap = *(const short8*)(pb + (16 * w + m15) * 72 + kk * 32 + g * 8);
      short8 bv8 = *(const short8*)(vT + (h * 8 + (m15 & 7)) * 72 + kk * 32 + g * 8);
      xacc = __builtin_amdgcn_mfma_f32_16x16x32_bf16(ap, bv8, xacc, 0, 0, 0);
    }
    if (m15 < 8) {
#pragma unroll
      for (int r = 0; r < 4; r++)
        xo[(16 * w + g * 4 + r) * 72 + h * 8 + m15] = f2b(xacc[r]);
    }
  }

  // ---------- output projection; out via LDS f32 stage + coalesced nt stores ----------
  __syncthreads();  // all waves done reading kb/vT (cross-wave) -> reuse as fstage
  {
    float* fs = (float*)(kb);  // f32 [64][pitch 68]; 17408 B inside kb+vT region
    f32x4 acc[4];
#pragma unroll
    for (int nt = 0; nt < 4; nt++) {
      float bb = bo[nt * 16 + m15];
      acc[nt] = (f32x4){bb, bb, bb, bb};
    }
#pragma unroll
    for (int kk = 0; kk < 2; kk++) {
      short8 ax = *(const short8*)(xo + (16 * w + m15) * 72 + kk * 32 + g * 8);
#pragma unroll
      for (int nt = 0; nt < 4; nt++) {
        short8 bf = *(const short8*)(wso + (size_t)(kk * 4 + nt) * 512 + l * 8);
        acc[nt] = __builtin_amdgcn_mfma_f32_16x16x32_bf16(ax, bf, acc[nt], 0, 0, 0);
      }
    }
    // scatter f32 to LDS (wave-private rows), then read back coalesced
#pragma unroll
    for (int nt = 0; nt < 4; nt++)
#pragma unroll
      for (int r = 0; r < 4; r++)
        fs[(16 * w + g * 4 + r) * 68 + nt * 16 + m15] = acc[nt][r];
    float* ob = out + (size_t)bid * 4096;
#pragma unroll
    for (int ro = 0; ro < 4; ro++) {
      int row = 16 * w + ro * 4 + g;
      f32x4 v = *(const f32x4*)(fs + row * 68 + m15 * 4);
      __builtin_nontemporal_store(v, (f32x4*)(ob + row * 64 + m15 * 4));
    }
  }
}

extern "C" void kernel_launch(void* const* d_in, const int* in_sizes, int n_in,
                              void* d_out, int out_size, void* d_ws, size_t ws_size,
                              hipStream_t stream) {
  const float* query = (const float*)d_in[0];
  const float* key   = (const float*)d_in[1];
  const float* value = (const float*)d_in[2];
  const int*   mask  = (const int*)d_in[4];
  const float* Wq = (const float*)d_in[5];
  const float* bq = (const float*)d_in[6];
  const float* Wk = (const float*)d_in[7];
  const float* bk = (const float*)d_in[8];
  const float* Wv = (const float*)d_in[9];
  const float* bv = (const float*)d_in[10];
  const float* Wo = (const float*)d_in[11];
  const float* bo = (const float*)d_in[12];

  float* out = (float*)d_out;
  float* p_out = out + OUT_ELEMS;
  u16* ws = (u16*)d_ws;

  hipLaunchKernelGGL(prep_weights, dim3(128), dim3(256), 0, stream,
                     Wq, Wk, Wv, Wo, ws);
  hipLaunchKernelGGL(fused_attn, dim3(8192), dim3(256), 0, stream,
                     query, key, value, mask, ws, bq, bk, bv, bo, out, p_out);
}

// Round 12
// 311.114 us; speedup vs baseline: 1.0384x; 1.0384x over previous
//
#include <hip/hip_runtime.h>

// B=16, N=512, T=64, D=64, H=8, K=3, DK=8
// grid = 8192 blocks (one per (b,n)), 256 threads (4 waves), 3 blocks/CU
// R12 = R10 + async-STAGE split: k loads issued before conv-q, v loads before
// conv-k (register prefetch; LDS write after the barrier). Barrier count unchanged.

#define OUT_ELEMS 33554432ull   // B*N*T*D

typedef unsigned short u16;
typedef unsigned int u32;
typedef __attribute__((ext_vector_type(8))) short short8;
typedef __attribute__((ext_vector_type(4))) float f32x4;

__device__ __forceinline__ u16 f2b(float f) {  // f32 -> bf16 RNE
  u32 u = __float_as_uint(f);
  return (u16)((u + 0x7fffu + ((u >> 16) & 1u)) >> 16);
}
__device__ __forceinline__ float b2f_lo(u32 u) { return __uint_as_float(u << 16); }
__device__ __forceinline__ float b2f_hi(u32 u) { return __uint_as_float(u & 0xffff0000u); }

// ws (ushort) layout, MFMA fragment order (lane l = (idx>>3)&63, elem e = idx&7):
//  wsq [0,12288):     frag f=(j*2+kk)*4+nt : Wq[d=nt*16+(l&15)][c=kk*32+(l>>4)*8+e][j]
//  wsk [12288,24576): same for Wk
//  wsv [24576,28672): frag f=w*2+kk (A-op): Wv[d=16w+(l&15)][c=kk*32+(l>>4)*8+e]
//  wso [28672,32768): frag f=kk*4+nt (B-op): Wo[dp=nt*16+(l&15)][c=kk*32+(l>>4)*8+e]
__global__ __launch_bounds__(256) void prep_weights(
    const float* __restrict__ Wq, const float* __restrict__ Wk,
    const float* __restrict__ Wv, const float* __restrict__ Wo,
    u16* __restrict__ ws) {
  int i = blockIdx.x * 256 + threadIdx.x;  // 0..32767
  int lane = (i >> 3) & 63;
  int e = i & 7;
  int m15 = lane & 15, g = lane >> 4;
  if (i < 12288) {
    int f = i >> 9;  // 0..23
    int j = f >> 3, kk = (f >> 2) & 1, nt = f & 3;
    int d = nt * 16 + m15, c = kk * 32 + g * 8 + e;
    ws[i] = f2b(Wq[(d * 64 + c) * 3 + j]);
  } else if (i < 24576) {
    int f = (i - 12288) >> 9;
    int j = f >> 3, kk = (f >> 2) & 1, nt = f & 3;
    int d = nt * 16 + m15, c = kk * 32 + g * 8 + e;
    ws[i] = f2b(Wk[(d * 64 + c) * 3 + j]);
  } else if (i < 28672) {
    int f = (i - 24576) >> 9;  // 0..7
    int w = f >> 1, kk = f & 1;
    int d = 16 * w + m15, c = kk * 32 + g * 8 + e;
    ws[i] = f2b(Wv[d * 64 + c]);
  } else if (i < 32768) {
    int f = (i - 28672) >> 9;  // 0..7
    int kk = f >> 2, nt = f & 3;
    int dp = nt * 16 + m15, c = kk * 32 + g * 8 + e;
    ws[i] = f2b(Wo[dp * 64 + c]);
  }
}

__global__ __launch_bounds__(256, 3) void fused_attn(
    const float* __restrict__ q_in, const float* __restrict__ k_in,
    const float* __restrict__ v_in, const int* __restrict__ mask,
    const u16* __restrict__ ws,
    const float* __restrict__ bq, const float* __restrict__ bk,
    const float* __restrict__ bv, const float* __restrict__ bo,
    float* __restrict__ out, float* __restrict__ p_out) {
  // LDS tiles: row pitch 72 bf16 (144B, 16B-aligned). xb rows 0,1 = zero pad.
  __shared__ __align__(16) u16 xb[66 * 72];  // staging; rows 0..63 alias pb later
  __shared__ __align__(16) u16 qb[64 * 72];  // q (scaled) [t][d]
  __shared__ __align__(16) u16 kb[64 * 72];  // k [s][d]
  __shared__ __align__(16) u16 vT[64 * 72];  // v^T [d][s]
  __shared__ __align__(16) u16 xo[64 * 72];  // attn out x [t][d]

  const int tid = threadIdx.x;
  const int bid = blockIdx.x;   // b*512 + n
  const int b = bid >> 9;
  const int l = tid & 63;
  const int w = tid >> 6;       // wave 0..3
  const int g = l >> 4;         // lane group 0..3
  const int m15 = l & 15;

  const u16* wsq = ws;
  const u16* wsk = ws + 12288;
  const u16* wsv = ws + 24576;
  const u16* wso = ws + 28672;

  const short8 z8 = {0, 0, 0, 0, 0, 0, 0, 0};

  // zero xb pad rows 0,1: 2 rows * 72 u16 = 144 u16 = 72 dwords
  if (tid < 72) ((u32*)xb)[tid] = 0u;

  // ---------- staging split: issue loads early, LDS-write late ----------
  auto stage_load = [&](const float* __restrict__ src, float4* rr) {
#pragma unroll
    for (int cc = 0; cc < 2; cc++) {
      const float* p = src + (tid * 2 + cc) * 8;
      rr[cc * 2 + 0] = *(const float4*)(p);
      rr[cc * 2 + 1] = *(const float4*)(p + 4);
    }
  };
  auto stage_write = [&](const float4* rr) {
#pragma unroll
    for (int cc = 0; cc < 2; cc++) {
      int c = tid * 2 + cc;
      float4 x0 = rr[cc * 2 + 0];
      float4 x1 = rr[cc * 2 + 1];
      u32 p0 = (u32)f2b(x0.x) | ((u32)f2b(x0.y) << 16);
      u32 p1 = (u32)f2b(x0.z) | ((u32)f2b(x0.w) << 16);
      u32 p2 = (u32)f2b(x1.x) | ((u32)f2b(x1.y) << 16);
      u32 p3 = (u32)f2b(x1.z) | ((u32)f2b(x1.w) << 16);
      int rw = c >> 3, k8 = (c & 7) * 8;
      *(uint4*)(xb + (rw + 2) * 72 + k8) = make_uint4(p0, p1, p2, p3);
    }
  };

  auto conv = [&](const u16* __restrict__ wpack, const float* __restrict__ bias,
                  float scale, u16* __restrict__ dst) {
    f32x4 acc[4];
#pragma unroll
    for (int nt = 0; nt < 4; nt++) {
      float bb = bias[nt * 16 + m15];
      acc[nt] = (f32x4){bb, bb, bb, bb};
    }
#pragma unroll
    for (int j = 0; j < 3; j++) {
#pragma unroll
      for (int kk = 0; kk < 2; kk++) {
        short8 a = *(const short8*)(xb + (16 * w + m15 + j) * 72 + kk * 32 + g * 8);
#pragma unroll
        for (int nt = 0; nt < 4; nt++) {
          short8 bf = *(const short8*)(wpack + (size_t)((j * 2 + kk) * 4 + nt) * 512 + l * 8);
          acc[nt] = __builtin_amdgcn_mfma_f32_16x16x32_bf16(a, bf, acc[nt], 0, 0, 0);
        }
      }
    }
#pragma unroll
    for (int nt = 0; nt < 4; nt++)
#pragma unroll
      for (int r = 0; r < 4; r++)
        dst[(16 * w + g * 4 + r) * 72 + nt * 16 + m15] = f2b(acc[nt][r] * scale);
  };

  // ---------- prologue with register prefetch ----------
  {
    float4 rq[4];
    stage_load(q_in + (size_t)bid * 4096, rq);
    stage_write(rq);
  }
  __syncthreads();
  float4 rk[4];
  stage_load(k_in + (size_t)bid * 4096, rk);   // k loads fly under conv-q
  conv(wsq, bq, 0.35355339059327373f, qb);
  __syncthreads();
  stage_write(rk);
  __syncthreads();
  float4 rv[4];
  stage_load(v_in + (size_t)bid * 4096, rv);   // v loads fly under conv-k
  conv(wsk, bk, 1.0f, kb);
  __syncthreads();
  stage_write(rv);
  __syncthreads();
  // ---------- v-proj -> vT[d][s] ----------
  {
    f32x4 acc[4];
    float bm0 = bv[16 * w + g * 4 + 0], bm1 = bv[16 * w + g * 4 + 1];
    float bm2 = bv[16 * w + g * 4 + 2], bm3 = bv[16 * w + g * 4 + 3];
#pragma unroll
    for (int nt = 0; nt < 4; nt++) acc[nt] = (f32x4){bm0, bm1, bm2, bm3};
#pragma unroll
    for (int kk = 0; kk < 2; kk++) {
      short8 a = *(const short8*)(wsv + (size_t)(w * 2 + kk) * 512 + l * 8);
#pragma unroll
      for (int nt = 0; nt < 4; nt++) {
        short8 bf = *(const short8*)(xb + (nt * 16 + m15 + 2) * 72 + kk * 32 + g * 8);
        acc[nt] = __builtin_amdgcn_mfma_f32_16x16x32_bf16(a, bf, acc[nt], 0, 0, 0);
      }
    }
#pragma unroll
    for (int nt = 0; nt < 4; nt++)
#pragma unroll
      for (int r = 0; r < 4; r++)
        vT[(16 * w + g * 4 + r) * 72 + nt * 16 + m15] = f2b(acc[nt][r]);
  }

  // mask bits: bit nt*4+r = mask[b][t=16w+g*4+r][s=nt*16+m15]
  u32 mb = 0;
#pragma unroll
  for (int nt = 0; nt < 4; nt++)
#pragma unroll
    for (int r = 0; r < 4; r++)
      if (mask[(size_t)b * 4096 + (16 * w + g * 4 + r) * 64 + nt * 16 + m15])
        mb |= 1u << (nt * 4 + r);
  __syncthreads();  // vT complete (cross-wave); xb free -> pb

  u16* pb = xb;  // P staging [t][s] bf16, rows 0..63; intra-wave use only

  // ---------- head loop: ZERO barriers (qb/pb/xo rows are wave-private; vT,kb read-only) ----------
#pragma unroll 1
  for (int h = 0; h < 8; h++) {
    // QK^T: K=8 padded to 32 (only lane-group 0 carries data)
    short8 aq = *(const short8*)(qb + (16 * w + m15) * 72 + h * 8);
    if (g != 0) aq = z8;
    f32x4 s4[4];
#pragma unroll
    for (int nt = 0; nt < 4; nt++) {
      short8 bk8 = *(const short8*)(kb + (nt * 16 + m15) * 72 + h * 8);
      if (g != 0) bk8 = z8;
      f32x4 zero = {0.f, 0.f, 0.f, 0.f};
      s4[nt] = __builtin_amdgcn_mfma_f32_16x16x32_bf16(aq, bk8, zero, 0, 0, 0);
    }
    // masked softmax over s (row = t fixed per (g,r); cols across 16 lanes x 4 nt)
    float e[4][4];
    float rs0 = 0.f, rs1 = 0.f, rs2 = 0.f, rs3 = 0.f;
#pragma unroll
    for (int nt = 0; nt < 4; nt++) {
      e[nt][0] = (mb & (1u << (nt * 4 + 0))) ? __expf(s4[nt][0]) : 0.f;
      e[nt][1] = (mb & (1u << (nt * 4 + 1))) ? __expf(s4[nt][1]) : 0.f;
      e[nt][2] = (mb & (1u << (nt * 4 + 2))) ? __expf(s4[nt][2]) : 0.f;
      e[nt][3] = (mb & (1u << (nt * 4 + 3))) ? __expf(s4[nt][3]) : 0.f;
      rs0 += e[nt][0]; rs1 += e[nt][1]; rs2 += e[nt][2]; rs3 += e[nt][3];
    }
#pragma unroll
    for (int off = 1; off <= 8; off <<= 1) {
      rs0 += __shfl_xor(rs0, off);
      rs1 += __shfl_xor(rs1, off);
      rs2 += __shfl_xor(rs2, off);
      rs3 += __shfl_xor(rs3, off);
    }
    float ri0 = __fdividef(1.f, rs0 + 1e-30f);
    float ri1 = __fdividef(1.f, rs1 + 1e-30f);
    float ri2 = __fdividef(1.f, rs2 + 1e-30f);
    float ri3 = __fdividef(1.f, rs3 + 1e-30f);
    // write P (bf16) to LDS; p_out produced from pb below, coalesced + nontemporal
#pragma unroll
    for (int nt = 0; nt < 4; nt++) {
      pb[(16 * w + g * 4 + 0) * 72 + nt * 16 + m15] = f2b(e[nt][0] * ri0);
      pb[(16 * w + g * 4 + 1) * 72 + nt * 16 + m15] = f2b(e[nt][1] * ri1);
      pb[(16 * w + g * 4 + 2) * 72 + nt * 16 + m15] = f2b(e[nt][2] * ri2);
      pb[(16 * w + g * 4 + 3) * 72 + nt * 16 + m15] = f2b(e[nt][3] * ri3);
    }
    // coalesced p_out: lane l -> row 16w + ro*4 + g, cols m15*4..+3
    // per instruction: 64 lanes cover 1024B contiguous (8 full 128B lines)
    float* pg = p_out + (((size_t)bid * 8 + h) * 4096);
#pragma unroll
    for (int ro = 0; ro < 4; ro++) {
      int row = 16 * w + ro * 4 + g;
      uint2 pv2 = *(const uint2*)(pb + row * 72 + m15 * 4);
      f32x4 f = {b2f_lo(pv2.x), b2f_hi(pv2.x), b2f_lo(pv2.y), b2f_hi(pv2.y)};
      __builtin_nontemporal_store(f, (f32x4*)(pg + row * 64 + m15 * 4));
    }
    // PV: x[t][h*8+dk] = sum_s P[t][s] v[s][h*8+dk]; N-cols 8..15 duplicated, discarded
    f32x4 xacc = {0.f, 0.f, 0.f, 0.f};
#pragma unroll
    for (int kk = 0; kk < 2; kk++) {
      short8 ap = *(const short8*)(pb + (16 * w + m15) * 72 + kk * 32 + g * 8);
      short8 bv8 = *(const short8*)(vT + (h * 8 + (m15 & 7)) * 72 + kk * 32 + g * 8);
      xacc = __builtin_amdgcn_mfma_f32_16x16x32_bf16(ap, bv8, xacc, 0, 0, 0);
    }
    if (m15 < 8) {
#pragma unroll
      for (int r = 0; r < 4; r++)
        xo[(16 * w + g * 4 + r) * 72 + h * 8 + m15] = f2b(xacc[r]);
    }
  }

  // ---------- output projection (xo rows are wave-private; no barrier) ----------
  {
    f32x4 acc[4];
#pragma unroll
    for (int nt = 0; nt < 4; nt++) {
      float bb = bo[nt * 16 + m15];
      acc[nt] = (f32x4){bb, bb, bb, bb};
    }
#pragma unroll
    for (int kk = 0; kk < 2; kk++) {
      short8 ax = *(const short8*)(xo + (16 * w + m15) * 72 + kk * 32 + g * 8);
#pragma unroll
      for (int nt = 0; nt < 4; nt++) {
        short8 bf = *(const short8*)(wso + (size_t)(kk * 4 + nt) * 512 + l * 8);
        acc[nt] = __builtin_amdgcn_mfma_f32_16x16x32_bf16(ax, bf, acc[nt], 0, 0, 0);
      }
    }
#pragma unroll
    for (int nt = 0; nt < 4; nt++)
#pragma unroll
      for (int r = 0; r < 4; r++)
        out[(size_t)bid * 4096 + (16 * w + g * 4 + r) * 64 + nt * 16 + m15] = acc[nt][r];
  }
}

extern "C" void kernel_launch(void* const* d_in, const int* in_sizes, int n_in,
                              void* d_out, int out_size, void* d_ws, size_t ws_size,
                              hipStream_t stream) {
  const float* query = (const float*)d_in[0];
  const float* key   = (const float*)d_in[1];
  const float* value = (const float*)d_in[2];
  const int*   mask  = (const int*)d_in[4];
  const float* Wq = (const float*)d_in[5];
  const float* bq = (const float*)d_in[6];
  const float* Wk = (const float*)d_in[7];
  const float* bk = (const float*)d_in[8];
  const float* Wv = (const float*)d_in[9];
  const float* bv = (const float*)d_in[10];
  const float* Wo = (const float*)d_in[11];
  const float* bo = (const float*)d_in[12];

  float* out = (float*)d_out;
  float* p_out = out + OUT_ELEMS;
  u16* ws = (u16*)d_ws;

  hipLaunchKernelGGL(prep_weights, dim3(128), dim3(256), 0, stream,
                     Wq, Wk, Wv, Wo, ws);
  hipLaunchKernelGGL(fused_attn, dim3(8192), dim3(256), 0, stream,
                     query, key, value, mask, ws, bq, bk, bv, bo, out, p_out);
}